// Round 13
// baseline (151.918 us; speedup 1.0000x reference)
//
#include <hip/hip_runtime.h>

typedef float f32x4 __attribute__((ext_vector_type(4)));
typedef short bf16x8 __attribute__((ext_vector_type(8)));
typedef unsigned int u32;
typedef unsigned short u16;

constexpr int T_ = 32768;
constexpr int D_ = 2048;
constexpr int E_ = 64;
constexpr int KSEL = 6;
constexpr float ROUTE_SCALE_ = 1.0f;

constexpr int ROWS = 64;            // rows per block; 16 waves = 4 rg x 2 K-half x 2 e-half
constexpr int DK = 32;              // k per chunk
constexpr int NCHH = 1024 / DK;     // 32 chunks per K-half
constexpr int WBUF = 12288;         // one W chunk: 12 frags x 1KB (3 planes x 4 frags)
constexpr int HSTRIDE = 2 * WBUF;   // per-half dbuf region; LDS total = 49152

// round-to-nearest-even fp32 -> bf16 (same split values as R4/R10/R12)
__device__ __forceinline__ u16 f2bf(float f) {
  u32 u = __float_as_uint(f);
  return (u16)((u + 0x7fffu + ((u >> 16) & 1u)) >> 16);
}
__device__ __forceinline__ float bf2f(u16 h) { return __uint_as_float(((u32)h) << 16); }

// ---- W pre-split (bytes identical to R10/R11/R12's ws) ----
// byte: c2*WBUF + (nfq*3 + p)*1024 + lane*16   (c2 = 0..63)
// lane elem j = plane_p(W[e][k]), e = nfq*16+(lane&15), k = c2*32 + (lane>>4)*8 + j
__global__ void wsplit_kernel(const float* __restrict__ W, char* __restrict__ ws) {
  int g = blockIdx.x * 256 + threadIdx.x;
  if (g >= 64 * 256) return;                   // 16384 threads
  int lane = g & 63, nfq = (g >> 6) & 3, c2 = g >> 8;
  int e = nfq * 16 + (lane & 15);
  int k0 = c2 * 32 + ((lane >> 4) << 3);
  const float* src = W + (size_t)e * D_ + k0;
  f32x4 a0 = *(const f32x4*)src;
  f32x4 a1 = *(const f32x4*)(src + 4);
  float f[8] = {a0.x, a0.y, a0.z, a0.w, a1.x, a1.y, a1.z, a1.w};
  bf16x8 h, m, l;
#pragma unroll
  for (int j = 0; j < 8; ++j) {
    u16 hb = f2bf(f[j]); float r1 = f[j] - bf2f(hb);   // exact
    u16 mb = f2bf(r1);   float r2 = r1 - bf2f(mb);     // exact
    u16 lb = f2bf(r2);
    h[j] = (short)hb; m[j] = (short)mb; l[j] = (short)lb;
  }
  char* dst = ws + (size_t)c2 * WBUF + (size_t)(nfq * 3) * 1024 + lane * 16;
  *(bf16x8*)(dst)        = h;
  *(bf16x8*)(dst + 1024) = m;
  *(bf16x8*)(dst + 2048) = l;
}

__device__ __forceinline__ void gload16(const void* g, void* l) {
  __builtin_amdgcn_global_load_lds(
      (const __attribute__((address_space(1))) void*)g,
      (__attribute__((address_space(3))) void*)l, 16, 0, 0);
}

__launch_bounds__(1024, 2)
__global__ void gate_kernel(const float* __restrict__ x, const char* __restrict__ ws,
                            float* __restrict__ out) {
  __shared__ __align__(16) char sm[2 * HSTRIDE];   // 49152 B -> 2 blocks/CU

  const int tid = threadIdx.x;
  const int lane = tid & 63;
  const int wv = tid >> 6;                 // 0..15
  const int wl = wv & 3;                   // row group: rows [wl*16, wl*16+16)
  const int half = (wv >> 2) & 1;          // K-half: k in [half*1024, +1024)
  const int eh = wv >> 3;                  // expert half: experts [eh*32, eh*32+32)
  const int r0 = blockIdx.x * ROWS;

  // per-lane x base: row = r0 + wl*16 + (lane&15), k = half*1024 + (lane>>4)*8
  // (eh=0/1 wave pairs load identical lines -> L1 serves the duplicate)
  const float* xp = x + (size_t)(r0 + wl * 16 + (lane & 15)) * D_
                      + half * 1024 + ((lane >> 4) << 3);

  f32x4 xA[2], xB[2];                      // two static reg banks (chunk c, c+1)

#define XLOAD(BANK, C)                                            \
  { const float* p_ = xp + (size_t)(C) * DK;                      \
    BANK[0] = *(const f32x4*)(p_); BANK[1] = *(const f32x4*)(p_ + 4); }

  // staging: the 8 eh=0 waves stage exactly as R12 (4 waves per half, 3 gloads each).
  // LDS dst wave-uniform (HW adds lane*16); global src per-lane.
  auto wgload = [&](int c2) {
    const char* src = ws + (size_t)(half * NCHH + c2) * WBUF
                         + (size_t)(wl * 64 + lane) * 16;               // per-lane
    char* dstb = sm + half * HSTRIDE + (c2 & 1) * WBUF + (size_t)(wl * 64) * 16;  // uniform
#pragma unroll
    for (int it = 0; it < 3; ++it)
      gload16(src + it * 4096, dstb + it * 4096);
  };

  f32x4 acc[2] = {};                       // this wave's 2 expert-quadrants

  // split one reg bank (8 floats) + 12 MFMA against this half's wbuf[c&1].
  // Per-accumulator chain identical to R12 -> bit-identical logits.
#define STEP(BANK, C)                                                          \
  {                                                                            \
    bf16x8 ah, am, al;                                                         \
    {                                                                          \
      f32x4 a0 = BANK[0], a1 = BANK[1];                                        \
      float f[8] = {a0.x, a0.y, a0.z, a0.w, a1.x, a1.y, a1.z, a1.w};           \
      _Pragma("unroll")                                                        \
      for (int j = 0; j < 8; ++j) {                                            \
        float v = f[j];                                                        \
        u32 uh = __float_as_uint(v) & 0xffff0000u;                             \
        float r1 = v - __uint_as_float(uh);                                    \
        u32 um = __float_as_uint(r1) & 0xffff0000u;                            \
        float r2 = r1 - __uint_as_float(um);                                   \
        u32 ul = __float_as_uint(r2);                                          \
        ah[j] = (short)(uh >> 16);                                             \
        am[j] = (short)(um >> 16);                                             \
        al[j] = (short)(ul >> 16);                                             \
      }                                                                        \
    }                                                                          \
    const char* wb = sm + half * HSTRIDE + ((C) & 1) * WBUF + lane * 16;       \
    _Pragma("unroll")                                                          \
    for (int n = 0; n < 2; ++n) {                                              \
      const char* fb = wb + (size_t)((eh * 2 + n) * 3) * 1024;                 \
      bf16x8 bh = *(const bf16x8*)(fb);                                        \
      bf16x8 bm = *(const bf16x8*)(fb + 1024);                                 \
      bf16x8 bl = *(const bf16x8*)(fb + 2048);                                 \
      f32x4 c_ = acc[n];                                                       \
      c_ = __builtin_amdgcn_mfma_f32_16x16x32_bf16(al, bh, c_, 0, 0, 0);       \
      c_ = __builtin_amdgcn_mfma_f32_16x16x32_bf16(am, bm, c_, 0, 0, 0);       \
      c_ = __builtin_amdgcn_mfma_f32_16x16x32_bf16(ah, bl, c_, 0, 0, 0);       \
      c_ = __builtin_amdgcn_mfma_f32_16x16x32_bf16(am, bh, c_, 0, 0, 0);       \
      c_ = __builtin_amdgcn_mfma_f32_16x16x32_bf16(ah, bm, c_, 0, 0, 0);       \
      c_ = __builtin_amdgcn_mfma_f32_16x16x32_bf16(ah, bh, c_, 0, 0, 0);       \
      acc[n] = c_;                                                             \
    }                                                                          \
  }

  // prologue
  XLOAD(xA, 0)
  XLOAD(xB, 1)
  if (eh == 0) wgload(0);

  // main loop: one __syncthreads per chunk; every load it drains is >=1 phase old
  for (int cc = 0; cc < NCHH; cc += 2) {
    __syncthreads();
    if (eh == 0 && cc + 1 < NCHH) wgload(cc + 1);
    STEP(xA, cc)
    if (cc + 2 < NCHH) XLOAD(xA, cc + 2)
    __syncthreads();
    if (eh == 0 && cc + 2 < NCHH) wgload(cc + 2);
    STEP(xB, cc + 1)
    if (cc + 3 < NCHH) XLOAD(xB, cc + 3)
  }

  // ---- partial logits to LDS: SL[half][row][e] (32KB, reuses wbuf region) ----
  __syncthreads();                         // all STEP reads of wbuf done
  float* SL = (float*)sm;
#pragma unroll
  for (int n = 0; n < 2; ++n)
#pragma unroll
    for (int j = 0; j < 4; ++j) {
      int r = wl * 16 + ((lane >> 4) << 2) + j;
      SL[half * (ROWS * E_) + r * E_ + eh * 32 + n * 16 + (lane & 15)] = acc[n][j];
    }
  __syncthreads();

  // ---- reduce halves + proven top-k epilogue: 4 rows per wave, lane = expert ----
  float* outI = out;
  float* outW = out + (size_t)T_ * KSEL;
  for (int rr = 0; rr < 4; ++rr) {
    const int r = wv * 4 + rr;
    const float lg = SL[r * E_ + lane] + SL[ROWS * E_ + r * E_ + lane];
    float mx = lg;
#pragma unroll
    for (int off = 32; off; off >>= 1) mx = fmaxf(mx, __shfl_xor(mx, off, 64));
    const float p = expf(lg - mx);
    float ssum = p;
#pragma unroll
    for (int off = 32; off; off >>= 1) ssum += __shfl_xor(ssum, off, 64);
    float prob = p / ssum;

    const int rg = r0 + r;
#pragma unroll
    for (int kk = 0; kk < KSEL; ++kk) {
      float v = prob; int idx = lane;
#pragma unroll
      for (int off = 32; off; off >>= 1) {
        float ov = __shfl_xor(v, off, 64);
        int oi = __shfl_xor(idx, off, 64);
        if (ov > v || (ov == v && oi < idx)) { v = ov; idx = oi; }
      }
      const float wsel = __shfl(lg, idx, 64);
      if (lane == 0) {
        outI[(size_t)rg * KSEL + kk] = (float)idx;
        outW[(size_t)rg * KSEL + kk] = wsel * ROUTE_SCALE_;
      }
      if (lane == idx) prob = -1.0f;
    }
  }
#undef XLOAD
#undef STEP
}

extern "C" void kernel_launch(void* const* d_in, const int* in_sizes, int n_in,
                              void* d_out, int out_size, void* d_ws, size_t ws_size,
                              hipStream_t stream) {
  const float* x = (const float*)d_in[0];
  const float* W = (const float*)d_in[1];
  char* ws = (char*)d_ws;                  // 64 * 12288 = 786432 bytes
  float* out = (float*)d_out;
  wsplit_kernel<<<dim3(64), dim3(256), 0, stream>>>(W, ws);
  gate_kernel<<<dim3(T_ / ROWS), dim3(1024), 0, stream>>>(x, ws, out);
}

// Round 14
// 131.510 us; speedup vs baseline: 1.1552x; 1.1552x over previous
//
#include <hip/hip_runtime.h>

typedef float f32x4 __attribute__((ext_vector_type(4)));
typedef short bf16x8 __attribute__((ext_vector_type(8)));
typedef unsigned int u32;
typedef unsigned short u16;

constexpr int T_ = 32768;
constexpr int D_ = 2048;
constexpr int E_ = 64;
constexpr int KSEL = 6;
constexpr float ROUTE_SCALE_ = 1.0f;

constexpr int ROWS = 64;            // block: 4 waves = 2 row-groups(32 rows) x 2 K-halves
constexpr int DK = 32;              // k per chunk
constexpr int NCHH = 1024 / DK;     // 32 chunks per K-half
constexpr int WBUF = 12288;         // one W chunk: 12 frags x 1KB
constexpr int HSTRIDE = 2 * WBUF;   // per-half dbuf; LDS total = 49152

__device__ __forceinline__ u16 f2bf(float f) {
  u32 u = __float_as_uint(f);
  return (u16)((u + 0x7fffu + ((u >> 16) & 1u)) >> 16);
}
__device__ __forceinline__ float bf2f(u16 h) { return __uint_as_float(((u32)h) << 16); }

// ---- W pre-split (bytes identical to R10/R12) ----
// byte: c2*WBUF + (nfq*3 + p)*1024 + lane*16   (c2 = 0..63)
// lane elem j = plane_p(W[e][k]), e = nfq*16+(lane&15), k = c2*32 + (lane>>4)*8 + j
__global__ void wsplit_kernel(const float* __restrict__ W, char* __restrict__ ws) {
  int g = blockIdx.x * 256 + threadIdx.x;
  if (g >= 64 * 256) return;                   // 16384 threads
  int lane = g & 63, nfq = (g >> 6) & 3, c2 = g >> 8;
  int e = nfq * 16 + (lane & 15);
  int k0 = c2 * 32 + ((lane >> 4) << 3);
  const float* src = W + (size_t)e * D_ + k0;
  f32x4 a0 = *(const f32x4*)src;
  f32x4 a1 = *(const f32x4*)(src + 4);
  float f[8] = {a0.x, a0.y, a0.z, a0.w, a1.x, a1.y, a1.z, a1.w};
  bf16x8 h, m, l;
#pragma unroll
  for (int j = 0; j < 8; ++j) {
    u16 hb = f2bf(f[j]); float r1 = f[j] - bf2f(hb);   // exact
    u16 mb = f2bf(r1);   float r2 = r1 - bf2f(mb);     // exact
    u16 lb = f2bf(r2);
    h[j] = (short)hb; m[j] = (short)mb; l[j] = (short)lb;
  }
  char* dst = ws + (size_t)c2 * WBUF + (size_t)(nfq * 3) * 1024 + lane * 16;
  *(bf16x8*)(dst)        = h;
  *(bf16x8*)(dst + 1024) = m;
  *(bf16x8*)(dst + 2048) = l;
}

__device__ __forceinline__ void gload16(const void* g, void* l) {
  __builtin_amdgcn_global_load_lds(
      (const __attribute__((address_space(1))) void*)g,
      (__attribute__((address_space(3))) void*)l, 16, 0, 0);
}

__launch_bounds__(256, 2)
__global__ void gate_kernel(const float* __restrict__ x, const char* __restrict__ ws,
                            float* __restrict__ out) {
  __shared__ __align__(16) char sm[2 * HSTRIDE];   // 49152 B

  const int tid = threadIdx.x;
  const int lane = tid & 63;
  const int wv = tid >> 6;                 // 0..3
  const int wl = wv & 1;                   // row group: rows [wl*32, wl*32+32)
  const int half = wv >> 1;                // K-half: k in [half*1024, +1024)
  const int r0 = blockIdx.x * ROWS;

  // per-lane x base: rows r0+wl*32+(lane&15) and +16 ; k = half*1024 + (lane>>4)*8
  const float* xp = x + (size_t)(r0 + wl * 32 + (lane & 15)) * D_
                      + half * 1024 + ((lane >> 4) << 3);

  f32x4 xA[4], xB[4];   // banks: [0,1]=rows mf0, [2,3]=rows mf1 (16 floats each bank)

#define XLOAD(BANK, C)                                                       \
  { const float* p_ = xp + (size_t)(C) * DK;                                 \
    BANK[0] = *(const f32x4*)(p_);               BANK[1] = *(const f32x4*)(p_ + 4); \
    BANK[2] = *(const f32x4*)(p_ + 16 * D_);     BANK[3] = *(const f32x4*)(p_ + 16 * D_ + 4); }

  // staging: 2 waves per half, 6 slices of 1KB each (12KB chunk).
  // LDS dst wave-uniform (HW adds lane*16); global src per-lane.
  auto wgload = [&](int c2) {
    const char* srcb = ws + (size_t)(half * NCHH + c2) * WBUF;
    char* dstb = sm + half * HSTRIDE + (c2 & 1) * WBUF;
#pragma unroll
    for (int it = 0; it < 6; ++it) {
      const int slice = wl * 6 + it;
      gload16(srcb + (size_t)(slice * 64 + lane) * 16, dstb + (size_t)slice * 1024);
    }
  };

  f32x4 acc[2][4] = {};                    // [A-frag mf][expert-quadrant n]

  // split both A-frag banks + 48 MFMA against this half's wbuf[c&1].
  // Per-accumulator chain identical to R12 -> bit-identical logits.
#define STEP(BANK, C)                                                          \
  {                                                                            \
    bf16x8 ah[2], am[2], al[2];                                                \
    _Pragma("unroll")                                                          \
    for (int mf = 0; mf < 2; ++mf) {                                           \
      f32x4 a0 = BANK[2 * mf], a1 = BANK[2 * mf + 1];                          \
      float f[8] = {a0.x, a0.y, a0.z, a0.w, a1.x, a1.y, a1.z, a1.w};           \
      _Pragma("unroll")                                                        \
      for (int j = 0; j < 8; ++j) {                                            \
        float v = f[j];                                                        \
        u32 uh = __float_as_uint(v) & 0xffff0000u;                             \
        float r1 = v - __uint_as_float(uh);                                    \
        u32 um = __float_as_uint(r1) & 0xffff0000u;                            \
        float r2 = r1 - __uint_as_float(um);                                   \
        u32 ul = __float_as_uint(r2);                                          \
        ah[mf][j] = (short)(uh >> 16);                                         \
        am[mf][j] = (short)(um >> 16);                                         \
        al[mf][j] = (short)(ul >> 16);                                         \
      }                                                                        \
    }                                                                          \
    const char* wb = sm + half * HSTRIDE + ((C) & 1) * WBUF + lane * 16;       \
    _Pragma("unroll")                                                          \
    for (int n = 0; n < 4; ++n) {                                              \
      const char* fb = wb + (size_t)(n * 3) * 1024;                            \
      bf16x8 bh = *(const bf16x8*)(fb);                                        \
      bf16x8 bm = *(const bf16x8*)(fb + 1024);                                 \
      bf16x8 bl = *(const bf16x8*)(fb + 2048);                                 \
      _Pragma("unroll")                                                        \
      for (int mf = 0; mf < 2; ++mf) {                                         \
        f32x4 c_ = acc[mf][n];                                                 \
        c_ = __builtin_amdgcn_mfma_f32_16x16x32_bf16(al[mf], bh, c_, 0, 0, 0); \
        c_ = __builtin_amdgcn_mfma_f32_16x16x32_bf16(am[mf], bm, c_, 0, 0, 0); \
        c_ = __builtin_amdgcn_mfma_f32_16x16x32_bf16(ah[mf], bl, c_, 0, 0, 0); \
        c_ = __builtin_amdgcn_mfma_f32_16x16x32_bf16(am[mf], bh, c_, 0, 0, 0); \
        c_ = __builtin_amdgcn_mfma_f32_16x16x32_bf16(ah[mf], bm, c_, 0, 0, 0); \
        c_ = __builtin_amdgcn_mfma_f32_16x16x32_bf16(ah[mf], bh, c_, 0, 0, 0); \
        acc[mf][n] = c_;                                                       \
      }                                                                        \
    }                                                                          \
  }

  // prologue
  XLOAD(xA, 0)
  XLOAD(xB, 1)
  wgload(0);

  // main loop: one __syncthreads per chunk; every load it drains is >=1 phase old
  for (int cc = 0; cc < NCHH; cc += 2) {
    __syncthreads();
    if (cc + 1 < NCHH) wgload(cc + 1);
    STEP(xA, cc)
    if (cc + 2 < NCHH) XLOAD(xA, cc + 2)
    __syncthreads();
    if (cc + 2 < NCHH) wgload(cc + 2);
    STEP(xB, cc + 1)
    if (cc + 3 < NCHH) XLOAD(xB, cc + 3)
  }

  // ---- partial logits to LDS: SL[half][row][e] (32KB, reuses wbuf region) ----
  __syncthreads();                         // all STEP reads of wbuf done
  float* SL = (float*)sm;
#pragma unroll
  for (int mf = 0; mf < 2; ++mf)
#pragma unroll
    for (int n = 0; n < 4; ++n)
#pragma unroll
      for (int j = 0; j < 4; ++j) {
        int r = wl * 32 + mf * 16 + ((lane >> 4) << 2) + j;
        SL[half * (ROWS * E_) + r * E_ + n * 16 + (lane & 15)] = acc[mf][n][j];
      }
  __syncthreads();

  // ---- reduce halves + proven top-k epilogue: 16 rows per wave, lane = expert ----
  float* outI = out;
  float* outW = out + (size_t)T_ * KSEL;
  for (int rr = 0; rr < 16; ++rr) {
    const int r = wv * 16 + rr;
    const float lg = SL[r * E_ + lane] + SL[ROWS * E_ + r * E_ + lane];
    float mx = lg;
#pragma unroll
    for (int off = 32; off; off >>= 1) mx = fmaxf(mx, __shfl_xor(mx, off, 64));
    const float p = expf(lg - mx);
    float ssum = p;
#pragma unroll
    for (int off = 32; off; off >>= 1) ssum += __shfl_xor(ssum, off, 64);
    float prob = p / ssum;

    const int rg = r0 + r;
#pragma unroll
    for (int kk = 0; kk < KSEL; ++kk) {
      float v = prob; int idx = lane;
#pragma unroll
      for (int off = 32; off; off >>= 1) {
        float ov = __shfl_xor(v, off, 64);
        int oi = __shfl_xor(idx, off, 64);
        if (ov > v || (ov == v && oi < idx)) { v = ov; idx = oi; }
      }
      const float wsel = __shfl(lg, idx, 64);
      if (lane == 0) {
        outI[(size_t)rg * KSEL + kk] = (float)idx;
        outW[(size_t)rg * KSEL + kk] = wsel * ROUTE_SCALE_;
      }
      if (lane == idx) prob = -1.0f;
    }
  }
#undef XLOAD
#undef STEP
}

extern "C" void kernel_launch(void* const* d_in, const int* in_sizes, int n_in,
                              void* d_out, int out_size, void* d_ws, size_t ws_size,
                              hipStream_t stream) {
  const float* x = (const float*)d_in[0];
  const float* W = (const float*)d_in[1];
  char* ws = (char*)d_ws;                  // 64 * 12288 = 786432 bytes
  float* out = (float*)d_out;
  wsplit_kernel<<<dim3(64), dim3(256), 0, stream>>>(W, ws);
  gate_kernel<<<dim3(T_ / ROWS), dim3(256), 0, stream>>>(x, ws, out);
}

// Round 15
// 103.468 us; speedup vs baseline: 1.4683x; 1.2710x over previous
//
#include <hip/hip_runtime.h>

typedef float f32x4 __attribute__((ext_vector_type(4)));
typedef short bf16x8 __attribute__((ext_vector_type(8)));
typedef unsigned int u32;
typedef unsigned short u16;

constexpr int T_ = 32768;
constexpr int D_ = 2048;
constexpr int E_ = 64;
constexpr int KSEL = 6;
constexpr float ROUTE_SCALE_ = 1.0f;

constexpr int ROWS = 64;            // rows per block; 8 waves = 4 rg x 2 K-halves
constexpr int DK = 32;              // k per chunk
constexpr int NCHH = 1024 / DK;     // 32 chunks per K-half
constexpr int WBUF = 12288;         // one W chunk: 12 frags x 1KB
constexpr int HSTRIDE = 2 * WBUF;   // per-half dbuf; LDS total = 49152

__device__ __forceinline__ u16 f2bf(float f) {
  u32 u = __float_as_uint(f);
  return (u16)((u + 0x7fffu + ((u >> 16) & 1u)) >> 16);
}
__device__ __forceinline__ float bf2f(u16 h) { return __uint_as_float(((u32)h) << 16); }

// ---- W pre-split (bytes identical to R10/R12) ----
// byte: c2*WBUF + (nfq*3 + p)*1024 + lane*16   (c2 = 0..63)
// lane elem j = plane_p(W[e][k]), e = nfq*16+(lane&15), k = c2*32 + (lane>>4)*8 + j
__global__ void wsplit_kernel(const float* __restrict__ W, char* __restrict__ ws) {
  int g = blockIdx.x * 256 + threadIdx.x;
  if (g >= 64 * 256) return;                   // 16384 threads
  int lane = g & 63, nfq = (g >> 6) & 3, c2 = g >> 8;
  int e = nfq * 16 + (lane & 15);
  int k0 = c2 * 32 + ((lane >> 4) << 3);
  const float* src = W + (size_t)e * D_ + k0;
  f32x4 a0 = *(const f32x4*)src;
  f32x4 a1 = *(const f32x4*)(src + 4);
  float f[8] = {a0.x, a0.y, a0.z, a0.w, a1.x, a1.y, a1.z, a1.w};
  bf16x8 h, m, l;
#pragma unroll
  for (int j = 0; j < 8; ++j) {
    u16 hb = f2bf(f[j]); float r1 = f[j] - bf2f(hb);   // exact
    u16 mb = f2bf(r1);   float r2 = r1 - bf2f(mb);     // exact
    u16 lb = f2bf(r2);
    h[j] = (short)hb; m[j] = (short)mb; l[j] = (short)lb;
  }
  char* dst = ws + (size_t)c2 * WBUF + (size_t)(nfq * 3) * 1024 + lane * 16;
  *(bf16x8*)(dst)        = h;
  *(bf16x8*)(dst + 1024) = m;
  *(bf16x8*)(dst + 2048) = l;
}

__device__ __forceinline__ void gload16(const void* g, void* l) {
  __builtin_amdgcn_global_load_lds(
      (const __attribute__((address_space(1))) void*)g,
      (__attribute__((address_space(3))) void*)l, 16, 0, 0);
}

__launch_bounds__(512, 4)
__global__ void gate_kernel(const float* __restrict__ x, const char* __restrict__ ws,
                            float* __restrict__ out) {
  __shared__ __align__(16) char sm[2 * HSTRIDE];   // 49152 B

  const int tid = threadIdx.x;
  const int lane = tid & 63;
  const int wv = tid >> 6;                 // 0..7
  const int half = wv >> 2;                // K-half: k in [half*1024, +1024)
  const int wl = wv & 3;                   // row group: rows [wl*16, wl*16+16)
  const int r0 = blockIdx.x * ROWS;

  // per-lane x base: row = r0 + wl*16 + (lane&15), k = half*1024 + (lane>>4)*8
  const float* xp = x + (size_t)(r0 + wl * 16 + (lane & 15)) * D_
                      + half * 1024 + ((lane >> 4) << 3);

  f32x4 x0[2], x1[2], x2[2], x3[2];        // 4 static banks; chunk c -> bank c&3

#define XLOAD(BANK, C)                                            \
  { const float* p_ = xp + (size_t)(C) * DK;                      \
    BANK[0] = *(const f32x4*)(p_); BANK[1] = *(const f32x4*)(p_ + 4); }

  // per-half staging: 4 waves of the half co-stage its 12KB chunk.
  // LDS dst wave-uniform (HW adds lane*16); global src per-lane.
  auto wgload = [&](int c2) {
    const char* src = ws + (size_t)(half * NCHH + c2) * WBUF
                         + (size_t)(wl * 64 + lane) * 16;               // per-lane
    char* dstb = sm + half * HSTRIDE + (c2 & 1) * WBUF + (size_t)(wl * 64) * 16;  // uniform
#pragma unroll
    for (int it = 0; it < 3; ++it)
      gload16(src + it * 4096, dstb + it * 4096);
  };

  f32x4 acc[4] = {};                       // 4 expert-quadrants x 4 regs

  // split one reg bank (8 floats) + 24 MFMA against this half's wbuf[c&1]
  // (chain identical to R12 -> bit-identical logits)
#define STEP(BANK, C)                                                          \
  {                                                                            \
    bf16x8 ah, am, al;                                                         \
    {                                                                          \
      f32x4 a0 = BANK[0], a1 = BANK[1];                                        \
      float f[8] = {a0.x, a0.y, a0.z, a0.w, a1.x, a1.y, a1.z, a1.w};           \
      _Pragma("unroll")                                                        \
      for (int j = 0; j < 8; ++j) {                                            \
        float v = f[j];                                                        \
        u32 uh = __float_as_uint(v) & 0xffff0000u;                             \
        float r1 = v - __uint_as_float(uh);                                    \
        u32 um = __float_as_uint(r1) & 0xffff0000u;                            \
        float r2 = r1 - __uint_as_float(um);                                   \
        u32 ul = __float_as_uint(r2);                                          \
        ah[j] = (short)(uh >> 16);                                             \
        am[j] = (short)(um >> 16);                                             \
        al[j] = (short)(ul >> 16);                                             \
      }                                                                        \
    }                                                                          \
    const char* wb = sm + half * HSTRIDE + ((C) & 1) * WBUF + lane * 16;       \
    _Pragma("unroll")                                                          \
    for (int n = 0; n < 4; ++n) {                                              \
      const char* fb = wb + (size_t)(n * 3) * 1024;                            \
      bf16x8 bh = *(const bf16x8*)(fb);                                        \
      bf16x8 bm = *(const bf16x8*)(fb + 1024);                                 \
      bf16x8 bl = *(const bf16x8*)(fb + 2048);                                 \
      f32x4 c_ = acc[n];                                                       \
      c_ = __builtin_amdgcn_mfma_f32_16x16x32_bf16(al, bh, c_, 0, 0, 0);       \
      c_ = __builtin_amdgcn_mfma_f32_16x16x32_bf16(am, bm, c_, 0, 0, 0);       \
      c_ = __builtin_amdgcn_mfma_f32_16x16x32_bf16(ah, bl, c_, 0, 0, 0);       \
      c_ = __builtin_amdgcn_mfma_f32_16x16x32_bf16(am, bh, c_, 0, 0, 0);       \
      c_ = __builtin_amdgcn_mfma_f32_16x16x32_bf16(ah, bm, c_, 0, 0, 0);       \
      c_ = __builtin_amdgcn_mfma_f32_16x16x32_bf16(ah, bh, c_, 0, 0, 0);       \
      acc[n] = c_;                                                             \
    }                                                                          \
  }

  // PHASE(CUR,PRE,C): prefetch chunk C+2 into PRE at the TOP of the phase so the
  // STEP covers its HBM latency before the next barrier's vmcnt(0) drain.
  // PRE's old content (chunk C-2) was consumed at phase C-2 -> safe to overwrite.
#define PHASE(CUR, PRE, C)                                                     \
  __syncthreads();                                                             \
  if ((C) + 2 < NCHH) XLOAD(PRE, (C) + 2)                                      \
  if ((C) + 1 < NCHH) wgload((C) + 1);                                         \
  STEP(CUR, C)

  // prologue
  XLOAD(x0, 0)
  XLOAD(x1, 1)
  wgload(0);

  for (int cc = 0; cc < NCHH; cc += 4) {
    PHASE(x0, x2, cc)
    PHASE(x1, x3, cc + 1)
    PHASE(x2, x0, cc + 2)
    PHASE(x3, x1, cc + 3)
  }

  // ---- partial logits to LDS: SL[half][row][e] (32KB, reuses wbuf region) ----
  __syncthreads();                         // all STEP reads of wbuf done
  float* SL = (float*)sm;
#pragma unroll
  for (int n = 0; n < 4; ++n)
#pragma unroll
    for (int j = 0; j < 4; ++j) {
      int r = wl * 16 + ((lane >> 4) << 2) + j;
      SL[half * (ROWS * E_) + r * E_ + n * 16 + (lane & 15)] = acc[n][j];
    }
  __syncthreads();

  // ---- reduce halves + proven top-k epilogue: 8 rows per wave, lane = expert ----
  float* outI = out;
  float* outW = out + (size_t)T_ * KSEL;
  for (int rr = 0; rr < 8; ++rr) {
    const int r = wv * 8 + rr;
    const float lg = SL[r * E_ + lane] + SL[ROWS * E_ + r * E_ + lane];
    float mx = lg;
#pragma unroll
    for (int off = 32; off; off >>= 1) mx = fmaxf(mx, __shfl_xor(mx, off, 64));
    const float p = expf(lg - mx);
    float ssum = p;
#pragma unroll
    for (int off = 32; off; off >>= 1) ssum += __shfl_xor(ssum, off, 64);
    float prob = p / ssum;

    const int rg = r0 + r;
#pragma unroll
    for (int kk = 0; kk < KSEL; ++kk) {
      float v = prob; int idx = lane;
#pragma unroll
      for (int off = 32; off; off >>= 1) {
        float ov = __shfl_xor(v, off, 64);
        int oi = __shfl_xor(idx, off, 64);
        if (ov > v || (ov == v && oi < idx)) { v = ov; idx = oi; }
      }
      const float wsel = __shfl(lg, idx, 64);
      if (lane == 0) {
        outI[(size_t)rg * KSEL + kk] = (float)idx;
        outW[(size_t)rg * KSEL + kk] = wsel * ROUTE_SCALE_;
      }
      if (lane == idx) prob = -1.0f;
    }
  }
#undef XLOAD
#undef STEP
#undef PHASE
}

extern "C" void kernel_launch(void* const* d_in, const int* in_sizes, int n_in,
                              void* d_out, int out_size, void* d_ws, size_t ws_size,
                              hipStream_t stream) {
  const float* x = (const float*)d_in[0];
  const float* W = (const float*)d_in[1];
  char* ws = (char*)d_ws;                  // 64 * 12288 = 786432 bytes
  float* out = (float*)d_out;
  wsplit_kernel<<<dim3(64), dim3(256), 0, stream>>>(W, ws);
  gate_kernel<<<dim3(T_ / ROWS), dim3(512), 0, stream>>>(x, ws, out);
}

// Round 16
// 72.714 us; speedup vs baseline: 2.0893x; 1.4229x over previous
//
#include <hip/hip_runtime.h>

typedef float f32x4 __attribute__((ext_vector_type(4)));
typedef short bf16x8 __attribute__((ext_vector_type(8)));
typedef unsigned int u32;
typedef unsigned short u16;

constexpr int T_ = 32768;
constexpr int D_ = 2048;
constexpr int E_ = 64;
constexpr int KSEL = 6;
constexpr float ROUTE_SCALE_ = 1.0f;

constexpr int ROWS = 64;            // rows per block; 8 waves = 4 rg x 2 K-halves
constexpr int DK = 32;              // k per chunk
constexpr int NCHH = 1024 / DK;     // 32 chunks per K-half
constexpr int WBUF = 12288;         // one W chunk: 12 frags x 1KB
constexpr int HSTRIDE = 2 * WBUF;   // per-half dbuf; LDS total = 49152
constexpr int SLSTR = 66;           // padded row-stride of SL[half][e][row]

__device__ __forceinline__ u16 f2bf(float f) {
  u32 u = __float_as_uint(f);
  return (u16)((u + 0x7fffu + ((u >> 16) & 1u)) >> 16);
}
__device__ __forceinline__ float bf2f(u16 h) { return __uint_as_float(((u32)h) << 16); }

// ---- W pre-split (bytes identical to R10/R12) ----
__global__ void wsplit_kernel(const float* __restrict__ W, char* __restrict__ ws) {
  int g = blockIdx.x * 256 + threadIdx.x;
  if (g >= 64 * 256) return;                   // 16384 threads
  int lane = g & 63, nfq = (g >> 6) & 3, c2 = g >> 8;
  int e = nfq * 16 + (lane & 15);
  int k0 = c2 * 32 + ((lane >> 4) << 3);
  const float* src = W + (size_t)e * D_ + k0;
  f32x4 a0 = *(const f32x4*)src;
  f32x4 a1 = *(const f32x4*)(src + 4);
  float f[8] = {a0.x, a0.y, a0.z, a0.w, a1.x, a1.y, a1.z, a1.w};
  bf16x8 h, m, l;
#pragma unroll
  for (int j = 0; j < 8; ++j) {
    u16 hb = f2bf(f[j]); float r1 = f[j] - bf2f(hb);   // exact
    u16 mb = f2bf(r1);   float r2 = r1 - bf2f(mb);     // exact
    u16 lb = f2bf(r2);
    h[j] = (short)hb; m[j] = (short)mb; l[j] = (short)lb;
  }
  char* dst = ws + (size_t)c2 * WBUF + (size_t)(nfq * 3) * 1024 + lane * 16;
  *(bf16x8*)(dst)        = h;
  *(bf16x8*)(dst + 1024) = m;
  *(bf16x8*)(dst + 2048) = l;
}

__device__ __forceinline__ void gload16(const void* g, void* l) {
  __builtin_amdgcn_global_load_lds(
      (const __attribute__((address_space(1))) void*)g,
      (__attribute__((address_space(3))) void*)l, 16, 0, 0);
}

__launch_bounds__(512, 4)
__global__ void gate_kernel(const float* __restrict__ x, const char* __restrict__ ws,
                            float* __restrict__ out) {
  __shared__ __align__(16) char sm[2 * HSTRIDE];   // 49152 B

  const int tid = threadIdx.x;
  const int lane = tid & 63;
  const int wv = tid >> 6;                 // 0..7
  const int half = wv >> 2;                // K-half: k in [half*1024, +1024)
  const int wl = wv & 3;                   // row group: rows [wl*16, wl*16+16)
  const int r0 = blockIdx.x * ROWS;

  const float* xp = x + (size_t)(r0 + wl * 16 + (lane & 15)) * D_
                      + half * 1024 + ((lane >> 4) << 3);

  f32x4 xA[2], xB[2];                      // two static reg banks (chunk c, c+1)

#define XLOAD(BANK, C)                                            \
  { const float* p_ = xp + (size_t)(C) * DK;                      \
    BANK[0] = *(const f32x4*)(p_); BANK[1] = *(const f32x4*)(p_ + 4); }

  auto wgload = [&](int c2) {
    const char* src = ws + (size_t)(half * NCHH + c2) * WBUF
                         + (size_t)(wl * 64 + lane) * 16;               // per-lane
    char* dstb = sm + half * HSTRIDE + (c2 & 1) * WBUF + (size_t)(wl * 64) * 16;  // uniform
#pragma unroll
    for (int it = 0; it < 3; ++it)
      gload16(src + it * 4096, dstb + it * 4096);
  };

  f32x4 acc[4] = {};                       // 4 expert-quadrants x 4 regs

  // chain identical to R12 -> bit-identical logits
#define STEP(BANK, C)                                                          \
  {                                                                            \
    bf16x8 ah, am, al;                                                         \
    {                                                                          \
      f32x4 a0 = BANK[0], a1 = BANK[1];                                        \
      float f[8] = {a0.x, a0.y, a0.z, a0.w, a1.x, a1.y, a1.z, a1.w};           \
      _Pragma("unroll")                                                        \
      for (int j = 0; j < 8; ++j) {                                            \
        float v = f[j];                                                        \
        u32 uh = __float_as_uint(v) & 0xffff0000u;                             \
        float r1 = v - __uint_as_float(uh);                                    \
        u32 um = __float_as_uint(r1) & 0xffff0000u;                            \
        float r2 = r1 - __uint_as_float(um);                                   \
        u32 ul = __float_as_uint(r2);                                          \
        ah[j] = (short)(uh >> 16);                                             \
        am[j] = (short)(um >> 16);                                             \
        al[j] = (short)(ul >> 16);                                             \
      }                                                                        \
    }                                                                          \
    const char* wb = sm + half * HSTRIDE + ((C) & 1) * WBUF + lane * 16;       \
    _Pragma("unroll")                                                          \
    for (int n = 0; n < 4; ++n) {                                              \
      const char* fb = wb + (size_t)(n * 3) * 1024;                            \
      bf16x8 bh = *(const bf16x8*)(fb);                                        \
      bf16x8 bm = *(const bf16x8*)(fb + 1024);                                 \
      bf16x8 bl = *(const bf16x8*)(fb + 2048);                                 \
      f32x4 c_ = acc[n];                                                       \
      c_ = __builtin_amdgcn_mfma_f32_16x16x32_bf16(al, bh, c_, 0, 0, 0);       \
      c_ = __builtin_amdgcn_mfma_f32_16x16x32_bf16(am, bm, c_, 0, 0, 0);       \
      c_ = __builtin_amdgcn_mfma_f32_16x16x32_bf16(ah, bl, c_, 0, 0, 0);       \
      c_ = __builtin_amdgcn_mfma_f32_16x16x32_bf16(am, bh, c_, 0, 0, 0);       \
      c_ = __builtin_amdgcn_mfma_f32_16x16x32_bf16(ah, bm, c_, 0, 0, 0);       \
      c_ = __builtin_amdgcn_mfma_f32_16x16x32_bf16(ah, bh, c_, 0, 0, 0);       \
      acc[n] = c_;                                                             \
    }                                                                          \
  }

  // prologue + main loop: exactly R12's schedule (best measured)
  XLOAD(xA, 0)
  XLOAD(xB, 1)
  wgload(0);

  for (int cc = 0; cc < NCHH; cc += 2) {
    __syncthreads();
    if (cc + 1 < NCHH) wgload(cc + 1);
    STEP(xA, cc)
    if (cc + 2 < NCHH) XLOAD(xA, cc + 2)
    __syncthreads();
    if (cc + 2 < NCHH) wgload(cc + 2);
    STEP(xB, cc + 1)
    if (cc + 3 < NCHH) XLOAD(xB, cc + 3)
  }

  // ---- partial logits TRANSPOSED to LDS: SL[half][e][row], stride 66 ----
  __syncthreads();                         // all STEP reads of wbuf done
  float* SL = (float*)sm;
#pragma unroll
  for (int n = 0; n < 4; ++n)
#pragma unroll
    for (int j = 0; j < 4; ++j) {
      int r = wl * 16 + ((lane >> 4) << 2) + j;
      int e = n * 16 + (lane & 15);
      SL[half * (E_ * SLSTR) + e * SLSTR + r] = acc[n][j];
    }
  __syncthreads();

  // ---- softmax-free top-k (softmax is monotone -> top-k by logit; ties -> lower e
  // via strict > and ascending-e scan, matching jax.lax.top_k). wave 0, lane = row. ----
  if (wv == 0) {
    float tv[KSEL], ti[KSEL];
#pragma unroll
    for (int kk = 0; kk < KSEL; ++kk) { tv[kk] = -3.4e38f; ti[kk] = 0.f; }
    for (int e = 0; e < E_; ++e) {
      float v = SL[e * SLSTR + lane] + SL[E_ * SLSTR + e * SLSTR + lane];
      float vi = (float)e;
#pragma unroll
      for (int kk = 0; kk < KSEL; ++kk) {
        bool c = v > tv[kk];
        float nv = c ? v : tv[kk];  float dv = c ? tv[kk] : v;
        float ni = c ? vi : ti[kk]; float di = c ? ti[kk] : vi;
        tv[kk] = nv; v = dv; ti[kk] = ni; vi = di;
      }
    }
    const int rg = r0 + lane;
    float* outI = out;
    float* outW = out + (size_t)T_ * KSEL;
#pragma unroll
    for (int kk = 0; kk < KSEL; ++kk) {
      outI[(size_t)rg * KSEL + kk] = ti[kk];
      outW[(size_t)rg * KSEL + kk] = tv[kk] * ROUTE_SCALE_;
    }
  }
#undef XLOAD
#undef STEP
}

extern "C" void kernel_launch(void* const* d_in, const int* in_sizes, int n_in,
                              void* d_out, int out_size, void* d_ws, size_t ws_size,
                              hipStream_t stream) {
  const float* x = (const float*)d_in[0];
  const float* W = (const float*)d_in[1];
  char* ws = (char*)d_ws;                  // 64 * 12288 = 786432 bytes
  float* out = (float*)d_out;
  wsplit_kernel<<<dim3(64), dim3(256), 0, stream>>>(W, ws);
  gate_kernel<<<dim3(T_ / ROWS), dim3(512), 0, stream>>>(x, ws, out);
}